// Round 4
// baseline (39944.183 us; speedup 1.0000x reference)
//
#include <hip/hip_runtime.h>

// MetaLSTMDetector v4: self-timed dataflow, v1-proven primitives only.
//
// 32 blocks x 512 thr = 4 teams x 8 members. Team owns 16 batches (full MFMA
// N). Member owns gate-rows [m*128, m*128+128) of BOTH layers; weights live in
// VGPRs as bf16 A-frags (~205 regs -> 2 waves/SIMD, launch_bounds(512,2)).
// h0/h1 cross-block exchange: global buffers in B-FRAGMENT layout; producers
// store packed u32 (shfl-pair), consumers load u64 relaxed agent atomics
// straight into MFMA B-operands. Per-wave flags: RELEASE publish, relaxed
// poll (64 flags <-> 64 lanes, __all). No LDS, no __syncthreads, no inline
// asm, no templates/lambdas, no atomicsRMW, no early-return blocks.
// Schedule per step s: L0[s] (uses h0[s-1]); L1[s-1] (uses h0[s-1], h1[s-2]);
// head[s-2] (round-robin member (t&7)==m, wave 0); then poll+gather h0[s],
// h1[s-1]. Deadlock-free: poll targets exactly match unconditional publishes.

#define T_LEN 4096

typedef float f32x4  __attribute__((ext_vector_type(4)));
typedef short bf16x8 __attribute__((ext_vector_type(8)));

static __device__ __forceinline__ unsigned int f2bf(float f) {
  unsigned int u = __float_as_uint(f);
  u += 0x7fffu + ((u >> 16) & 1u);   // RNE
  return u >> 16;
}
static __device__ __forceinline__ float bf2f(unsigned short h) {
  return __uint_as_float(((unsigned int)h) << 16);
}
static __device__ __forceinline__ float sigm(float x)  { return 1.0f / (1.0f + __expf(-x)); }
static __device__ __forceinline__ float tanh_(float x) { return 2.0f / (1.0f + __expf(-2.0f * x)) - 1.0f; }

// d_ws is poisoned 0xAA before every launch; only the flags need zeroing
// (data buffers are gated by flags and fully rewritten before first read).
__global__ void init_ws_kernel(unsigned int* ws) {
  unsigned int i = threadIdx.x;
  if (i < 512u) ws[i] = 0u;   // 4 teams x 128 flag words (flag0[64], flag1[64])
}

__global__ __launch_bounds__(512, 2) void lstm_kernel(
    const float* __restrict__ y,
    const float* __restrict__ Wih0, const float* __restrict__ Whh0,
    const float* __restrict__ bih0, const float* __restrict__ bhh0,
    const float* __restrict__ Wih1, const float* __restrict__ Whh1,
    const float* __restrict__ bih1, const float* __restrict__ bhh1,
    const float* __restrict__ Wout, const float* __restrict__ bout,
    float* __restrict__ out, char* __restrict__ ws)
{
  const int bid  = blockIdx.x;      // 0..31
  const int team = bid >> 3;        // 0..3
  const int m    = bid & 7;         // member (M-split)
  const int tid  = threadIdx.x;
  const int w    = tid >> 6;        // wave 0..7
  const int l    = tid & 63;
  const int col  = l & 15;          // batch within team / MFMA column
  const int kg   = l >> 4;          // k-group

  // Gate-rows interleaved G[u*4+g]; this wave's 16-row tile: g = base + col.
  const int g = m * 128 + w * 16 + col;
  const int R = (g & 3) * 256 + (g >> 2);        // torch W row: gate*256 + unit
  const int u = m * 32 + w * 4 + kg;             // owned unit (C-frag lane)

  // ---- weight A-fragments (bf16, VGPR-resident) ----
  bf16x8 a0[8], a1h0[8], a1h1[8], a0x;
  #pragma unroll
  for (int kf = 0; kf < 8; ++kf) {
    bf16x8 v0, v1, v2;
    #pragma unroll
    for (int i = 0; i < 8; ++i) {
      int k = kf * 32 + kg * 8 + i;
      v0[i] = (short)f2bf(Whh0[R * 256 + k]);
      v1[i] = (short)f2bf(Wih1[R * 256 + k]);
      v2[i] = (short)f2bf(Whh1[R * 256 + k]);
    }
    a0[kf] = v0; a1h0[kf] = v1; a1h1[kf] = v2;
  }
  #pragma unroll
  for (int i = 0; i < 8; ++i) a0x[i] = 0;
  if (kg == 0) {
    #pragma unroll
    for (int i = 0; i < 4; ++i) a0x[i] = (short)f2bf(Wih0[R * 4 + i]);
    a0x[4] = (short)f2bf(bih0[R] + bhh0[R]);     // bias0 via x-frag k=4 (xf[4]=1)
  }
  float bias1[4];
  #pragma unroll
  for (int r = 0; r < 4; ++r) bias1[r] = bih1[r * 256 + u] + bhh1[r * 256 + u];
  const float bo0 = bout[0], bo1 = bout[1];

  // ---- exchange buffers: flags at ws[0..2KB), data at ws+4KB ----
  unsigned int* flag0 = (unsigned int*)ws + (size_t)team * 128;
  unsigned int* flag1 = flag0 + 64;
  char* tb = ws + 4096 + (size_t)team * 32768;
  unsigned int*   h0w = (unsigned int*)tb;             // [2][2048] u32 view
  unsigned int*   h1w = (unsigned int*)(tb + 16384);
  unsigned short* h0r = (unsigned short*)tb;           // u16 view for gathers
  unsigned short* h1r = (unsigned short*)(tb + 16384);
  // frag layout bytes: kf*1024 + kg*256 + col*16 + i*2  (u = kf*32 + kg*8 + i)
  const int pubw  = (u >> 5) * 256 + ((u >> 3) & 3) * 64 + col * 4 + ((u & 7) >> 1);
  const int ld16  = kg * 128 + col * 8;                // + kf*512 (u16 units)

  const float* yb = y + (size_t)(team * 16 + col) * T_LEN;
  float* outb = out + (size_t)(team * 16 + col) * T_LEN * 2;

  bf16x8 f_h0[8], f_h1[8];
  #pragma unroll
  for (int kf = 0; kf < 8; ++kf) {
    #pragma unroll
    for (int i = 0; i < 8; ++i) { f_h0[kf][i] = 0; f_h1[kf][i] = 0; }
  }

  float c0 = 0.f, c1 = 0.f;
  float xw0 = -100.f, xw1 = -100.f, xw2 = -100.f, xw3 = yb[0];
  float yn = yb[1];

  for (int s = 0; s <= T_LEN + 1; ++s) {
    // ---- A: layer 0, h0[s] ----
    if (s < T_LEN) {
      bf16x8 xf;
      #pragma unroll
      for (int i = 0; i < 8; ++i) xf[i] = 0;
      if (kg == 0) {
        xf[0] = (short)f2bf(xw0); xf[1] = (short)f2bf(xw1);
        xf[2] = (short)f2bf(xw2); xf[3] = (short)f2bf(xw3);
        xf[4] = (short)0x3F80;                   // 1.0 (bias lane)
      }
      f32x4 acc = {0.f, 0.f, 0.f, 0.f};
      acc = __builtin_amdgcn_mfma_f32_16x16x32_bf16(a0x, xf, acc, 0, 0, 0);
      #pragma unroll
      for (int kf = 0; kf < 8; ++kf)
        acc = __builtin_amdgcn_mfma_f32_16x16x32_bf16(a0[kf], f_h0[kf], acc, 0, 0, 0);
      c0 = sigm(acc[1]) * c0 + sigm(acc[0]) * tanh_(acc[2]);
      float h0n = sigm(acc[3]) * tanh_(c0);
      unsigned int hv = f2bf(h0n);
      unsigned int hi = __shfl_down(hv, 16, 64);  // partner unit u+1 (kg+1)
      if ((kg & 1) == 0)
        __hip_atomic_store(h0w + (s & 1) * 2048 + pubw, (hv & 0xffffu) | (hi << 16),
                           __ATOMIC_RELAXED, __HIP_MEMORY_SCOPE_AGENT);
      if (l == 0)
        __hip_atomic_store(&flag0[m * 8 + w], (unsigned int)(s + 1),
                           __ATOMIC_RELEASE, __HIP_MEMORY_SCOPE_AGENT);
    }
    // ---- B: layer 1, h1[s-1] ----
    if (s >= 1 && s <= T_LEN) {
      f32x4 acc = {bias1[0], bias1[1], bias1[2], bias1[3]};
      #pragma unroll
      for (int kf = 0; kf < 8; ++kf)
        acc = __builtin_amdgcn_mfma_f32_16x16x32_bf16(a1h0[kf], f_h0[kf], acc, 0, 0, 0);
      #pragma unroll
      for (int kf = 0; kf < 8; ++kf)
        acc = __builtin_amdgcn_mfma_f32_16x16x32_bf16(a1h1[kf], f_h1[kf], acc, 0, 0, 0);
      c1 = sigm(acc[1]) * c1 + sigm(acc[0]) * tanh_(acc[2]);
      float h1n = sigm(acc[3]) * tanh_(c1);
      unsigned int hv = f2bf(h1n);
      unsigned int hi = __shfl_down(hv, 16, 64);
      if ((kg & 1) == 0)
        __hip_atomic_store(h1w + ((s - 1) & 1) * 2048 + pubw, (hv & 0xffffu) | (hi << 16),
                           __ATOMIC_RELAXED, __HIP_MEMORY_SCOPE_AGENT);
      if (l == 0)
        __hip_atomic_store(&flag1[m * 8 + w], (unsigned int)s,
                           __ATOMIC_RELEASE, __HIP_MEMORY_SCOPE_AGENT);
    }
    // ---- C: head, out[t = s-2] (member (t&7)==m, wave 0; f_h1 = h1[s-2]) ----
    if (s >= 2 && w == 0 && ((s - 2) & 7) == m) {
      int t = s - 2;
      float p0 = 0.f, p1 = 0.f;
      #pragma unroll
      for (int kf = 0; kf < 8; ++kf) {
        #pragma unroll
        for (int i = 0; i < 8; ++i) {
          float hv = bf2f((unsigned short)f_h1[kf][i]);
          int k = kf * 32 + kg * 8 + i;
          p0 += hv * Wout[k];
          p1 += hv * Wout[256 + k];
        }
      }
      p0 += __shfl_xor(p0, 16, 64); p0 += __shfl_xor(p0, 32, 64);
      p1 += __shfl_xor(p1, 16, 64); p1 += __shfl_xor(p1, 32, 64);
      if (kg == 0) {
        float2 o = make_float2(p0 + bo0, p1 + bo1);
        *(float2*)(outb + (size_t)t * 2) = o;
      }
    }
    // ---- D: poll + gather next-state frags ----
    if (s <= T_LEN - 1) {            // h0[s] for L0[s+1] / L1[s] (at step s+1)
      int tgt = s + 1;
      int v = (int)__hip_atomic_load(&flag0[l], __ATOMIC_RELAXED, __HIP_MEMORY_SCOPE_AGENT);
      int it = 0;
      while (!__all(v >= tgt) && ++it < (1 << 22))
        v = (int)__hip_atomic_load(&flag0[l], __ATOMIC_RELAXED, __HIP_MEMORY_SCOPE_AGENT);
      const unsigned short* src = h0r + (s & 1) * 4096 + ld16;
      #pragma unroll
      for (int kf = 0; kf < 8; ++kf) {
        const unsigned long long* p = (const unsigned long long*)(src + kf * 512);
        unsigned long long q0 = __hip_atomic_load(p,     __ATOMIC_RELAXED, __HIP_MEMORY_SCOPE_AGENT);
        unsigned long long q1 = __hip_atomic_load(p + 1, __ATOMIC_RELAXED, __HIP_MEMORY_SCOPE_AGENT);
        union { unsigned long long q[2]; bf16x8 f; } uu;
        uu.q[0] = q0; uu.q[1] = q1;
        f_h0[kf] = uu.f;
      }
    }
    if (s >= 1 && s <= T_LEN) {      // h1[s-1] for L1[s] (at step s+1) + head
      int tgt = s;
      int v = (int)__hip_atomic_load(&flag1[l], __ATOMIC_RELAXED, __HIP_MEMORY_SCOPE_AGENT);
      int it = 0;
      while (!__all(v >= tgt) && ++it < (1 << 22))
        v = (int)__hip_atomic_load(&flag1[l], __ATOMIC_RELAXED, __HIP_MEMORY_SCOPE_AGENT);
      const unsigned short* src = h1r + ((s - 1) & 1) * 4096 + ld16;
      #pragma unroll
      for (int kf = 0; kf < 8; ++kf) {
        const unsigned long long* p = (const unsigned long long*)(src + kf * 512);
        unsigned long long q0 = __hip_atomic_load(p,     __ATOMIC_RELAXED, __HIP_MEMORY_SCOPE_AGENT);
        unsigned long long q1 = __hip_atomic_load(p + 1, __ATOMIC_RELAXED, __HIP_MEMORY_SCOPE_AGENT);
        union { unsigned long long q[2]; bf16x8 f; } uu;
        uu.q[0] = q0; uu.q[1] = q1;
        f_h1[kf] = uu.f;
      }
    }
    // ---- E: slide x window; prefetch y one step ahead ----
    xw0 = xw1; xw1 = xw2; xw2 = xw3; xw3 = yn;
    if (s + 2 < T_LEN) yn = yb[s + 2];
  }
}

extern "C" void kernel_launch(void* const* d_in, const int* in_sizes, int n_in,
                              void* d_out, int out_size, void* d_ws, size_t ws_size,
                              hipStream_t stream) {
  const float* y    = (const float*)d_in[0];
  const float* Wih0 = (const float*)d_in[1];
  const float* Whh0 = (const float*)d_in[2];
  const float* bih0 = (const float*)d_in[3];
  const float* bhh0 = (const float*)d_in[4];
  const float* Wih1 = (const float*)d_in[5];
  const float* Whh1 = (const float*)d_in[6];
  const float* bih1 = (const float*)d_in[7];
  const float* bhh1 = (const float*)d_in[8];
  const float* Wout = (const float*)d_in[9];
  const float* bout = (const float*)d_in[10];

  init_ws_kernel<<<dim3(1), dim3(512), 0, stream>>>((unsigned int*)d_ws);
  lstm_kernel<<<dim3(32), dim3(512), 0, stream>>>(
      y, Wih0, Whh0, bih0, bhh0, Wih1, Whh1, bih1, bhh1, Wout, bout,
      (float*)d_out, (char*)d_ws);
}